// Round 1
// baseline (231.192 us; speedup 1.0000x reference)
//
#include <hip/hip_runtime.h>

#define NROWS 8192
#define DIM   1024
#define EPSF  1e-8f

typedef __attribute__((ext_vector_type(4))) float f32x4;
typedef __attribute__((ext_vector_type(8))) short bf16x8;

typedef __attribute__((address_space(1))) void g_void;
typedef __attribute__((address_space(3))) void l_void;

__device__ __forceinline__ void async_copy16(void* lds, const void* g) {
  __builtin_amdgcn_global_load_lds((g_void*)const_cast<void*>(g), (l_void*)lds, 16, 0, 0);
}

__device__ __forceinline__ unsigned short f2bf(float f) {
  union { float f; unsigned u; } c; c.f = f;
  unsigned u = c.u;
  u += 0x7FFFu + ((u >> 16) & 1u);   // round-to-nearest-even
  return (unsigned short)(u >> 16);
}

// ---------------- Kernel A: row L2-normalize, cast to bf16, init maxenc ----------------
extern "C" __global__ __launch_bounds__(256)
void koleo_norm(const float* __restrict__ in, unsigned short* __restrict__ xb,
                unsigned* __restrict__ maxenc) {
  const int row = blockIdx.x;
  const int tid = threadIdx.x;
  const float4 v = reinterpret_cast<const float4*>(in + (size_t)row * DIM)[tid];
  float ss = v.x * v.x + v.y * v.y + v.z * v.z + v.w * v.w;
#pragma unroll
  for (int off = 32; off > 0; off >>= 1) ss += __shfl_down(ss, off);
  __shared__ float wsum[4];
  if ((tid & 63) == 0) wsum[tid >> 6] = ss;
  __syncthreads();
  const float total = wsum[0] + wsum[1] + wsum[2] + wsum[3];
  const float scale = 1.0f / (sqrtf(total) + EPSF);
  ushort4 o;
  o.x = f2bf(v.x * scale); o.y = f2bf(v.y * scale);
  o.z = f2bf(v.z * scale); o.w = f2bf(v.w * scale);
  reinterpret_cast<ushort4*>(xb + (size_t)row * DIM)[tid] = o;
  if (row < NROWS / 256) maxenc[row * 256 + tid] = 0u;  // enc(any real dot) > 0
}

// ---------------- Kernel B: Gram-max via bf16 MFMA, 128x128 tile, BK=64 ----------------
#define BM 128
#define BN 128
#define BK 64

extern "C" __global__ __launch_bounds__(256)
void koleo_grammax(const unsigned short* __restrict__ xb, unsigned* __restrict__ maxenc) {
  __shared__ unsigned short As[BM * BK];  // [128][64] linear, 16 KB
  __shared__ unsigned short Bs[BN * BK];
  __shared__ unsigned smax[BM];

  const int tid  = threadIdx.x;
  const int lane = tid & 63;
  const int wid  = tid >> 6;
  const int wr   = wid >> 1;     // wave row (0..1), each wave owns 64x64
  const int wc   = wid & 1;      // wave col
  const int lr   = lane & 15;
  const int lg   = lane >> 4;

  const int rowBase = blockIdx.y * BM;
  const int colBase = blockIdx.x * BN;

  f32x4 acc[4][4] = {};

  for (int kt = 0; kt < DIM / BK; ++kt) {
    const char* gA = (const char*)(xb + (size_t)rowBase * DIM + kt * BK);
    const char* gB = (const char*)(xb + (size_t)colBase * DIM + kt * BK);
#pragma unroll
    for (int r = 0; r < 4; ++r) {
      const int o   = r * 4096 + tid * 16;   // byte offset in 16KB tile
      const int row = o >> 7;                // 128 B per row
      const int cb  = o & 127;
      async_copy16((char*)As + o, gA + (size_t)row * (DIM * 2) + cb);
      async_copy16((char*)Bs + o, gB + (size_t)row * (DIM * 2) + cb);
    }
    __syncthreads();  // drains vmcnt for global_load_lds
#pragma unroll
    for (int kk = 0; kk < 2; ++kk) {
      bf16x8 a[4], b[4];
#pragma unroll
      for (int m = 0; m < 4; ++m)
        a[m] = *reinterpret_cast<const bf16x8*>(&As[(wr * 64 + m * 16 + lr) * BK + kk * 32 + lg * 8]);
#pragma unroll
      for (int n = 0; n < 4; ++n)
        b[n] = *reinterpret_cast<const bf16x8*>(&Bs[(wc * 64 + n * 16 + lr) * BK + kk * 32 + lg * 8]);
#pragma unroll
      for (int m = 0; m < 4; ++m)
#pragma unroll
        for (int n = 0; n < 4; ++n)
          acc[m][n] = __builtin_amdgcn_mfma_f32_16x16x32_bf16(a[m], b[n], acc[m][n], 0, 0, 0);
    }
    __syncthreads();
  }

  // ---- epilogue: per-row max with diagonal mask ----
  if (tid < BM) smax[tid] = 0u;
  __syncthreads();

#pragma unroll
  for (int m = 0; m < 4; ++m) {
#pragma unroll
    for (int r = 0; r < 4; ++r) {
      const int lrow = wr * 64 + m * 16 + lg * 4 + r;  // C/D: row=(lane>>4)*4+reg
      const int grow = rowBase + lrow;
      float mx = -2.0f;
#pragma unroll
      for (int n = 0; n < 4; ++n) {
        float v = acc[m][n][r];
        const int gcol = colBase + wc * 64 + n * 16 + lr;  // C/D: col=lane&15
        if (grow == gcol) v = -2.0f;                        // mask self-similarity
        mx = fmaxf(mx, v);
      }
      // max across the 16 lanes holding this row's columns
#pragma unroll
      for (int off = 1; off < 16; off <<= 1) mx = fmaxf(mx, __shfl_xor(mx, off));
      if (lr == 0) {
        const unsigned bits = __float_as_uint(mx);
        const unsigned enc  = (bits & 0x80000000u) ? ~bits : (bits | 0x80000000u);
        atomicMax(&smax[lrow], enc);
      }
    }
  }
  __syncthreads();
  if (tid < BM) atomicMax(&maxenc[rowBase + tid], smax[tid]);
}

// ---------------- Kernel C: loss reduction ----------------
extern "C" __global__ __launch_bounds__(256)
void koleo_loss(const unsigned* __restrict__ maxenc, float* __restrict__ out) {
  const int tid = threadIdx.x;
  float sum = 0.0f;
  for (int i = tid; i < NROWS; i += 256) {
    const unsigned u    = maxenc[i];
    const unsigned bits = (u & 0x80000000u) ? (u & 0x7FFFFFFFu) : ~u;
    const float m = __uint_as_float(bits);
    const float d = sqrtf(fmaxf(2.0f - 2.0f * m, 0.0f)) + EPSF;  // ||x_i - x_nn|| + eps
    sum += logf(d + EPSF);
  }
#pragma unroll
  for (int off = 32; off > 0; off >>= 1) sum += __shfl_down(sum, off);
  __shared__ float wsum[4];
  if ((tid & 63) == 0) wsum[tid >> 6] = sum;
  __syncthreads();
  if (tid == 0) out[0] = -(wsum[0] + wsum[1] + wsum[2] + wsum[3]) / (float)NROWS;
}

extern "C" void kernel_launch(void* const* d_in, const int* in_sizes, int n_in,
                              void* d_out, int out_size, void* d_ws, size_t ws_size,
                              hipStream_t stream) {
  const float* in = (const float*)d_in[0];
  unsigned short* xb = (unsigned short*)d_ws;                                  // 16 MB bf16 x
  unsigned* maxenc   = (unsigned*)((char*)d_ws + (size_t)NROWS * DIM * 2);     // 32 KB
  float* out = (float*)d_out;

  hipLaunchKernelGGL(koleo_norm,    dim3(NROWS),  dim3(256), 0, stream, in, xb, maxenc);
  hipLaunchKernelGGL(koleo_grammax, dim3(64, 64), dim3(256), 0, stream, xb, maxenc);
  hipLaunchKernelGGL(koleo_loss,    dim3(1),      dim3(256), 0, stream, maxenc, out);
}

// Round 2
// 152.777 us; speedup vs baseline: 1.5133x; 1.5133x over previous
//
#include <hip/hip_runtime.h>

#define NROWS 8192
#define DIM   1024
#define EPSF  1e-8f

typedef __attribute__((ext_vector_type(4))) float f32x4;
typedef __attribute__((ext_vector_type(8))) short bf16x8;

typedef __attribute__((address_space(1))) void g_void;
typedef __attribute__((address_space(3))) void l_void;

__device__ __forceinline__ void async_copy16(void* lds, const void* g) {
  __builtin_amdgcn_global_load_lds((g_void*)const_cast<void*>(g), (l_void*)lds, 16, 0, 0);
}

__device__ __forceinline__ unsigned short f2bf(float f) {
  union { float f; unsigned u; } c; c.f = f;
  unsigned u = c.u;
  u += 0x7FFFu + ((u >> 16) & 1u);   // round-to-nearest-even
  return (unsigned short)(u >> 16);
}

__device__ __forceinline__ unsigned encf(float f) {
  const unsigned bits = __float_as_uint(f);
  return (bits & 0x80000000u) ? ~bits : (bits | 0x80000000u);
}

// ---------------- Kernel A: row L2-normalize, cast to bf16, init maxenc ----------------
extern "C" __global__ __launch_bounds__(256)
void koleo_norm(const float* __restrict__ in, unsigned short* __restrict__ xb,
                unsigned* __restrict__ maxenc) {
  const int row = blockIdx.x;
  const int tid = threadIdx.x;
  const float4 v = reinterpret_cast<const float4*>(in + (size_t)row * DIM)[tid];
  float ss = v.x * v.x + v.y * v.y + v.z * v.z + v.w * v.w;
#pragma unroll
  for (int off = 32; off > 0; off >>= 1) ss += __shfl_down(ss, off);
  __shared__ float wsum[4];
  if ((tid & 63) == 0) wsum[tid >> 6] = ss;
  __syncthreads();
  const float total = wsum[0] + wsum[1] + wsum[2] + wsum[3];
  const float scale = 1.0f / (sqrtf(total) + EPSF);
  ushort4 o;
  o.x = f2bf(v.x * scale); o.y = f2bf(v.y * scale);
  o.z = f2bf(v.z * scale); o.w = f2bf(v.w * scale);
  reinterpret_cast<ushort4*>(xb + (size_t)row * DIM)[tid] = o;
  if (row < NROWS / 256) maxenc[row * 256 + tid] = 0u;  // enc(any real dot) > 0
}

// ---------------- Kernel B: upper-triangle Gram-max via bf16 MFMA ----------------
#define BM 128
#define BN 128
#define BK 64
#define NT (NROWS / BM)            // 64 tiles per dim
#define NBLK (NT * (NT + 1) / 2)   // 2080 upper-triangle blocks

extern "C" __global__ __launch_bounds__(256)
void koleo_grammax(const unsigned short* __restrict__ xb, unsigned* __restrict__ maxenc) {
  __shared__ unsigned short As[BM * BK];  // [128][64] linear, 16 KB
  __shared__ unsigned short Bs[BN * BK];
  __shared__ unsigned smaxr[BM];
  __shared__ unsigned smaxc[BN];

  const int tid  = threadIdx.x;
  const int lane = tid & 63;
  const int wid  = tid >> 6;
  const int wr   = wid >> 1;     // wave row (0..1), each wave owns 64x64
  const int wc   = wid & 1;      // wave col
  const int lr   = lane & 15;
  const int lg   = lane >> 4;

  // decode upper-triangle (i <= j) tile coords from linear bid
  const int bid = blockIdx.x;
  int ti = (int)((2.0f * NT + 1.0f -
                  sqrtf((float)((2 * NT + 1) * (2 * NT + 1) - 8 * bid))) * 0.5f);
  while ((ti + 1) * NT - ((ti + 1) * ti) / 2 <= bid) ++ti;
  while (ti * NT - (ti * (ti - 1)) / 2 > bid) --ti;
  const int tj = ti + (bid - (ti * NT - (ti * (ti - 1)) / 2));

  const int rowBase = ti * BM;
  const int colBase = tj * BN;
  const bool diag = (ti == tj);

  f32x4 acc[4][4] = {};

  for (int kt = 0; kt < DIM / BK; ++kt) {
    const char* gA = (const char*)(xb + (size_t)rowBase * DIM + kt * BK);
    const char* gB = (const char*)(xb + (size_t)colBase * DIM + kt * BK);
#pragma unroll
    for (int r = 0; r < 4; ++r) {
      const int o   = r * 4096 + tid * 16;   // byte offset in 16KB tile
      const int row = o >> 7;                // 128 B per row
      const int cb  = o & 127;
      async_copy16((char*)As + o, gA + (size_t)row * (DIM * 2) + cb);
      async_copy16((char*)Bs + o, gB + (size_t)row * (DIM * 2) + cb);
    }
    __syncthreads();  // drains vmcnt for global_load_lds
#pragma unroll
    for (int kk = 0; kk < 2; ++kk) {
      bf16x8 a[4], b[4];
#pragma unroll
      for (int m = 0; m < 4; ++m)
        a[m] = *reinterpret_cast<const bf16x8*>(&As[(wr * 64 + m * 16 + lr) * BK + kk * 32 + lg * 8]);
#pragma unroll
      for (int n = 0; n < 4; ++n)
        b[n] = *reinterpret_cast<const bf16x8*>(&Bs[(wc * 64 + n * 16 + lr) * BK + kk * 32 + lg * 8]);
#pragma unroll
      for (int m = 0; m < 4; ++m)
#pragma unroll
        for (int n = 0; n < 4; ++n)
          acc[m][n] = __builtin_amdgcn_mfma_f32_16x16x32_bf16(a[m], b[n], acc[m][n], 0, 0, 0);
    }
    __syncthreads();
  }

  // ---- epilogue ----
  if (tid < BM) { smaxr[tid] = 0u; smaxc[tid] = 0u; }
  __syncthreads();

  // per-row max (max over this block's columns), diagonal masked
#pragma unroll
  for (int m = 0; m < 4; ++m) {
#pragma unroll
    for (int r = 0; r < 4; ++r) {
      const int lrow = wr * 64 + m * 16 + lg * 4 + r;  // C/D: row=(lane>>4)*4+reg
      const int grow = rowBase + lrow;
      float mx = -2.0f;
#pragma unroll
      for (int n = 0; n < 4; ++n) {
        float v = acc[m][n][r];
        const int gcol = colBase + wc * 64 + n * 16 + lr;  // C/D: col=lane&15
        if (grow == gcol) v = -2.0f;                        // mask self-similarity
        mx = fmaxf(mx, v);
      }
#pragma unroll
      for (int off = 1; off < 16; off <<= 1) mx = fmaxf(mx, __shfl_xor(mx, off));
      if (lr == 0) atomicMax(&smaxr[lrow], encf(mx));
    }
  }

  // per-column max (max over this block's rows) — only needed off-diagonal;
  // diagonal blocks are symmetric so row-max already covers them
  if (!diag) {
#pragma unroll
    for (int n = 0; n < 4; ++n) {
      float mx = -2.0f;
#pragma unroll
      for (int m = 0; m < 4; ++m)
#pragma unroll
        for (int r = 0; r < 4; ++r) mx = fmaxf(mx, acc[m][n][r]);
      mx = fmaxf(mx, __shfl_xor(mx, 16));   // reduce across lg groups
      mx = fmaxf(mx, __shfl_xor(mx, 32));
      if (lg == 0) atomicMax(&smaxc[wc * 64 + n * 16 + lr], encf(mx));
    }
  }
  __syncthreads();
  if (tid < BM) {
    atomicMax(&maxenc[rowBase + tid], smaxr[tid]);
    if (!diag) atomicMax(&maxenc[colBase + tid], smaxc[tid]);
  }
}

// ---------------- Kernel C: loss reduction ----------------
extern "C" __global__ __launch_bounds__(256)
void koleo_loss(const unsigned* __restrict__ maxenc, float* __restrict__ out) {
  const int tid = threadIdx.x;
  float sum = 0.0f;
  for (int i = tid; i < NROWS; i += 256) {
    const unsigned u    = maxenc[i];
    const unsigned bits = (u & 0x80000000u) ? (u & 0x7FFFFFFFu) : ~u;
    const float m = __uint_as_float(bits);
    const float d = sqrtf(fmaxf(2.0f - 2.0f * m, 0.0f)) + EPSF;  // ||x_i - x_nn|| + eps
    sum += logf(d + EPSF);
  }
#pragma unroll
  for (int off = 32; off > 0; off >>= 1) sum += __shfl_down(sum, off);
  __shared__ float wsum[4];
  if ((tid & 63) == 0) wsum[tid >> 6] = sum;
  __syncthreads();
  if (tid == 0) out[0] = -(wsum[0] + wsum[1] + wsum[2] + wsum[3]) / (float)NROWS;
}

extern "C" void kernel_launch(void* const* d_in, const int* in_sizes, int n_in,
                              void* d_out, int out_size, void* d_ws, size_t ws_size,
                              hipStream_t stream) {
  const float* in = (const float*)d_in[0];
  unsigned short* xb = (unsigned short*)d_ws;                                  // 16 MB bf16 x
  unsigned* maxenc   = (unsigned*)((char*)d_ws + (size_t)NROWS * DIM * 2);     // 32 KB
  float* out = (float*)d_out;

  hipLaunchKernelGGL(koleo_norm,    dim3(NROWS), dim3(256), 0, stream, in, xb, maxenc);
  hipLaunchKernelGGL(koleo_grammax, dim3(NBLK),  dim3(256), 0, stream, xb, maxenc);
  hipLaunchKernelGGL(koleo_loss,    dim3(1),     dim3(256), 0, stream, maxenc, out);
}